// Round 7
// baseline (376.459 us; speedup 1.0000x reference)
//
#include <hip/hip_runtime.h>
#include <math.h>

#define CN 32    // classes
#define DN 128   // feature dim
#define BKT_SHIFT 9          // 512 nodes per bucket
#define BKT_NODES 512
#define CHUNK 8192           // edges per partition chunk
#define MAXBKT 1024
#define DCAP 12288           // max edges per bucket (mean 8192, ~45 sigma headroom)

// ---------------- softmax over C per node: 32 threads/node ----------------
__global__ void k_softmax(const float* __restrict__ logits, float* __restrict__ probs, int N) {
    int t = blockIdx.x * blockDim.x + threadIdx.x;
    int node = t >> 5, c = t & 31;
    if (node >= N) return;
    float l = logits[node * CN + c];
    float m = l;
    #pragma unroll
    for (int o = 16; o; o >>= 1) m = fmaxf(m, __shfl_xor(m, o, 32));
    float e = __expf(l - m);
    float s = e;
    #pragma unroll
    for (int o = 16; o; o >>= 1) s += __shfl_xor(s, o, 32);
    probs[node * CN + c] = e / s;
}

// ---- pass A: per-chunk bucket histogram. grid = NCH x 256 ----
__global__ void k_part_hist(const int* __restrict__ dst, int* __restrict__ M,
                            int E, int NBKT) {
    __shared__ int hist[MAXBKT];
    int t = threadIdx.x;
    for (int j = t; j < NBKT; j += 256) hist[j] = 0;
    __syncthreads();
    int ebeg = blockIdx.x * CHUNK;
    #pragma unroll
    for (int k = 0; k < CHUNK / 256; ++k) {
        int e = ebeg + k * 256 + t;
        if (e < E) atomicAdd(&hist[dst[e] >> BKT_SHIFT], 1);
    }
    __syncthreads();
    int* row = M + (size_t)blockIdx.x * NBKT;
    for (int j = t; j < NBKT; j += 256) row[j] = hist[j];
}

// ---- pass B: exclusive scan of M in bucket-major order ----
__global__ void k_part_scan(int* __restrict__ M, int* __restrict__ bbase,
                            int NCH, int NBKT, int E) {
    __shared__ int wsum[16], wpre[16];
    __shared__ int carry;
    int t = threadIdx.x, ln = t & 63, wv = t >> 6;
    if (t == 0) carry = 0;
    __syncthreads();
    int L = NCH * NBKT;
    for (int base = 0; base < L; base += 1024) {
        int k = base + t;
        int idx = 0, v = 0;
        if (k < L) {
            int b = k / NCH, ch = k - b * NCH;
            idx = ch * NBKT + b;
            v = M[idx];
        }
        int incl = v;
        #pragma unroll
        for (int o = 1; o < 64; o <<= 1) { int u = __shfl_up(incl, o, 64); if (ln >= o) incl += u; }
        if (ln == 63) wsum[wv] = incl;
        __syncthreads();
        if (t == 0) {
            int r = carry;
            #pragma unroll
            for (int w = 0; w < 16; ++w) { wpre[w] = r; r += wsum[w]; }
            carry = r;
        }
        __syncthreads();
        if (k < L) M[idx] = wpre[wv] + incl - v;
        __syncthreads();
    }
    for (int b = t; b < NBKT; b += 1024) bbase[b] = M[b];
    if (t == 0) bbase[NBKT] = E;
}

// ---- pass C: partition edges into bucket-major slices, packed (local<<17)|src ----
__global__ void k_part_scatter(const int* __restrict__ src, const int* __restrict__ dst,
                               const int* __restrict__ M, int* __restrict__ part,
                               int E, int NBKT) {
    __shared__ int cur[MAXBKT];
    int t = threadIdx.x;
    const int* row = M + (size_t)blockIdx.x * NBKT;
    for (int j = t; j < NBKT; j += 256) cur[j] = row[j];
    __syncthreads();
    int ebeg = blockIdx.x * CHUNK;
    #pragma unroll
    for (int k = 0; k < CHUNK / 256; ++k) {
        int e = ebeg + k * 256 + t;
        if (e < E) {
            int d = dst[e];
            int b = d >> BKT_SHIFT;
            int p = atomicAdd(&cur[b], 1);
            part[p] = ((d & (BKT_NODES - 1)) << 17) | src[e];
        }
    }
}

// ---- pass D: per-bucket LDS counting sort IN PLACE: part slice -> eidx slice ----
__global__ void k_bucket_csr(int* __restrict__ part, const int* __restrict__ bbase,
                             int* __restrict__ cnt, int* __restrict__ off, int N) {
    __shared__ int sbuf[DCAP];
    __shared__ int hcnt[BKT_NODES];
    __shared__ int wsum[8], wpre[8];
    int t = threadIdx.x, ln = t & 63, wv = t >> 6;
    int b = blockIdx.x;
    int lo = bbase[b], hi = bbase[b + 1];
    int n = hi - lo;
    if (n > DCAP) n = DCAP;                 // statistically unreachable
    for (int e = t; e < n; e += BKT_NODES) sbuf[e] = part[lo + e];
    hcnt[t] = 0;
    __syncthreads();
    for (int e = t; e < n; e += BKT_NODES) atomicAdd(&hcnt[sbuf[e] >> 17], 1);
    __syncthreads();
    int v = hcnt[t];
    int incl = v;
    #pragma unroll
    for (int o = 1; o < 64; o <<= 1) { int u = __shfl_up(incl, o, 64); if (ln >= o) incl += u; }
    if (ln == 63) wsum[wv] = incl;
    __syncthreads();
    if (t == 0) {
        int r = 0;
        #pragma unroll
        for (int w = 0; w < 8; ++w) { wpre[w] = r; r += wsum[w]; }
    }
    __syncthreads();
    int excl = wpre[wv] + incl - v;
    int g = b * BKT_NODES + t;
    if (g < N) { cnt[g] = v; off[g] = lo + excl; }
    hcnt[t] = excl;          // per-node cursor
    __syncthreads();
    for (int e = t; e < n; e += BKT_NODES) {
        int pk = sbuf[e];
        int p = atomicAdd(&hcnt[pk >> 17], 1);
        part[lo + p] = pk & 0x1FFFF;        // in-place: now eidx
    }
}

// ---- gather probs + KL/entropy + per-block LN partials: 32 threads/node ----
__global__ void k_probs_f(const float* __restrict__ probs, const int* __restrict__ off,
                          const int* __restrict__ cnt, const int* __restrict__ eidx,
                          float* __restrict__ f1buf, float* __restrict__ f2buf,
                          double* __restrict__ pbuf, int N) {
    int t = blockIdx.x * blockDim.x + threadIdx.x;
    int i = t >> 5, c = t & 31;
    float f1 = 0.f, f2 = 0.f;
    if (i < N) {
        int beg = off[i], dg = cnt[i];
        float sum = 0.f;
        for (int base = 0; base < dg; base += 16) {
            int rem = dg - base;
            int lim = rem < 16 ? rem : 16;
            int myi = (c < lim) ? eidx[beg + base + c] : 0;
            #pragma unroll
            for (int j = 0; j < 16; ++j) {
                int s = __shfl(myi, j, 32);
                float v = probs[(size_t)s * CN + c];
                sum += (j < rem) ? v : 0.f;
            }
        }
        float f1c = 0.f, f2c = 0.f;
        if (dg > 0) {
            float p = probs[(size_t)i * CN + c];
            float mp = sum / (float)dg;
            float lm = logf(mp + 1e-9f);
            f1c = p * (logf(p + 1e-9f) - lm);
            f2c = -mp * lm;
        }
        #pragma unroll
        for (int o = 16; o; o >>= 1) { f1c += __shfl_xor(f1c, o, 32); f2c += __shfl_xor(f2c, o, 32); }
        if (c == 0) { f1buf[i] = f1c; f2buf[i] = f2c; f1 = f1c; f2 = f2c; }
    }
    double v0 = f1, v1 = (double)f1 * f1, v2 = f2, v3 = (double)f2 * f2;
    #pragma unroll
    for (int o = 32; o; o >>= 1) {
        v0 += __shfl_down(v0, o, 64);
        v1 += __shfl_down(v1, o, 64);
        v2 += __shfl_down(v2, o, 64);
        v3 += __shfl_down(v3, o, 64);
    }
    __shared__ double sh[4][4];
    int wave = threadIdx.x >> 6, lane = threadIdx.x & 63;
    if (lane == 0) { sh[0][wave] = v0; sh[1][wave] = v1; sh[2][wave] = v2; sh[3][wave] = v3; }
    __syncthreads();
    if (threadIdx.x == 0) {
        double a = 0, b = 0, c2 = 0, d = 0;
        #pragma unroll
        for (int w = 0; w < 4; ++w) { a += sh[0][w]; b += sh[1][w]; c2 += sh[2][w]; d += sh[3][w]; }
        double* p = pbuf + (size_t)blockIdx.x * 4;
        p[0] = a; p[1] = b; p[2] = c2; p[3] = d;
    }
}

// ---- deterministic single-block reduction of block partials -> stats ----
__global__ void k_redstats(const double* __restrict__ pbuf, double* __restrict__ stats, int nblk) {
    int t = threadIdx.x;
    double a = 0, b = 0, c = 0, d = 0;
    for (int k = t; k < nblk; k += blockDim.x) {
        const double* p = pbuf + (size_t)k * 4;
        a += p[0]; b += p[1]; c += p[2]; d += p[3];
    }
    #pragma unroll
    for (int o = 32; o; o >>= 1) {
        a += __shfl_down(a, o, 64);
        b += __shfl_down(b, o, 64);
        c += __shfl_down(c, o, 64);
        d += __shfl_down(d, o, 64);
    }
    __shared__ double sh[4][16];
    int wv = t >> 6, ln = t & 63;
    if (ln == 0) { sh[0][wv] = a; sh[1][wv] = b; sh[2][wv] = c; sh[3][wv] = d; }
    __syncthreads();
    if (t == 0) {
        double s0 = 0, s1 = 0, s2 = 0, s3 = 0;
        int nw = blockDim.x >> 6;
        for (int w = 0; w < nw; ++w) { s0 += sh[0][w]; s1 += sh[1][w]; s2 += sh[2][w]; s3 += sh[3][w]; }
        stats[0] = s0; stats[1] = s1; stats[2] = s2; stats[3] = s3;
    }
}

// ---------------- per-node gating: z, gate = min(old_z, z) ----------------
__global__ void k_z(const float* __restrict__ f1buf, const float* __restrict__ f2buf,
                    const double* __restrict__ stats, const float* __restrict__ old_z,
                    const float* __restrict__ tau1, const float* __restrict__ tau2,
                    float* __restrict__ z_out, float* __restrict__ gate, int N) {
    int i = blockIdx.x * blockDim.x + threadIdx.x;
    if (i >= N) return;
    double invN = 1.0 / (double)N;
    float mu1 = (float)(stats[0] * invN);
    float var1 = (float)(stats[1] * invN) - mu1 * mu1;
    float is1 = rsqrtf(var1 + 1e-5f);
    float mu2 = (float)(stats[2] * invN);
    float var2 = (float)(stats[3] * invN) - mu2 * mu2;
    float is2 = rsqrtf(var2 + 1e-5f);
    float a = (f1buf[i] - mu1) * is1;
    float b = (f2buf[i] - mu2) * is2;
    float z = (1.f / (1.f + __expf(a - tau1[0]))) * (1.f / (1.f + __expf(b - tau2[0])));
    z_out[i] = z;
    gate[i] = fminf(old_z[i], z);
}

// ---- gather h + epilogue, COLUMN-SLICED & XCD-PINNED ----
// Block b: slice = b & 7 (16 cols, 64 B = one cache line per row access);
// nodes [ (b>>3)*16, +16 ). Round-robin dispatch pins slice s to XCD s, so
// each XCD's L2 works on a 6.4 MB column-slice of h instead of all 51 MB.
__global__ void k_gather_cs(const float* __restrict__ h, const int* __restrict__ off,
                            const int* __restrict__ cnt, const int* __restrict__ eidx,
                            const float* __restrict__ gate, const float* __restrict__ norm,
                            float* __restrict__ out, int N) {
    int t = threadIdx.x;
    int grp = t >> 4, c = t & 15;            // 16 node-groups x 16 lanes
    int slice = blockIdx.x & 7;
    int i = (blockIdx.x >> 3) * 16 + grp;
    if (i >= N) return;
    int col = slice * 16 + c;
    int beg = off[i], dg = cnt[i];
    float acc = 0.f;
    for (int base = 0; base < dg; base += 16) {
        int rem = dg - base;
        int lim = rem < 16 ? rem : 16;
        int myi = (c < lim) ? __builtin_nontemporal_load(&eidx[beg + base + c]) : 0;
        #pragma unroll
        for (int j = 0; j < 16; ++j) {
            int s = __shfl(myi, j, 16);
            float v = h[(size_t)s * DN + col];     // 16 lanes = one 64B line
            acc += (j < rem) ? v : 0.f;
        }
    }
    float g = gate[i], nm = norm[i];
    float hv = h[(size_t)i * DN + col];
    float r = hv + g * fmaxf(acc * nm, 0.f);
    __builtin_nontemporal_store(r, &out[(size_t)i * DN + col]);  // don't evict h
}

extern "C" void kernel_launch(void* const* d_in, const int* in_sizes, int n_in,
                              void* d_out, int out_size, void* d_ws, size_t ws_size,
                              hipStream_t stream) {
    const float* h      = (const float*)d_in[0];
    const float* logits = (const float*)d_in[1];
    const float* old_z  = (const float*)d_in[2];
    const float* norm   = (const float*)d_in[3];
    const float* tau1   = (const float*)d_in[4];
    const float* tau2   = (const float*)d_in[5];
    const int*   src    = (const int*)d_in[6];
    const int*   dst    = (const int*)d_in[7];
    const int N = in_sizes[2];   // old_z length
    const int E = in_sizes[6];   // src length

    float* out   = (float*)d_out;            // [N*DN] new_h, then [N] z
    float* z_out = out + (size_t)N * DN;

    const int B = 256;
    const int NBF  = (N * CN + B - 1) / B;            // blocks of k_probs_f
    const int NBKT = (N + BKT_NODES - 1) >> BKT_SHIFT;
    const int NCH  = (E + CHUNK - 1) / CHUNK;

    // workspace layout
    char*   ws    = (char*)d_ws;
    double* stats = (double*)ws;                         // 64 B
    int*    cnt   = (int*)(ws + 64);                     // N
    int*    off   = cnt + N;                             // N
    int*    bbase = off + N;                             // MAXBKT+8
    int*    M     = bbase + MAXBKT + 8;                  // NCH*NBKT
    int*    eidx  = M + (size_t)NCH * NBKT;              // E (part, sorted in place)
    float*  probs = (float*)(eidx + E);                  // N*CN
    float*  f1buf = probs + (size_t)N * CN;              // N
    float*  f2buf = f1buf + N;                           // N
    float*  gate  = f2buf + N;                           // N
    double* pbuf  = (double*)(((size_t)(gate + N) + 15) & ~(size_t)15);  // NBF*4

    k_softmax<<<(N * CN + B - 1) / B, B, 0, stream>>>(logits, probs, N);

    k_part_hist<<<NCH, 256, 0, stream>>>(dst, M, E, NBKT);
    k_part_scan<<<1, 1024, 0, stream>>>(M, bbase, NCH, NBKT, E);
    k_part_scatter<<<NCH, 256, 0, stream>>>(src, dst, M, eidx, E, NBKT);
    k_bucket_csr<<<NBKT, BKT_NODES, 0, stream>>>(eidx, bbase, cnt, off, N);

    k_probs_f<<<NBF, B, 0, stream>>>(probs, off, cnt, eidx, f1buf, f2buf, pbuf, N);
    k_redstats<<<1, 1024, 0, stream>>>(pbuf, stats, NBF);
    k_z<<<(N + B - 1) / B, B, 0, stream>>>(f1buf, f2buf, stats, old_z, tau1, tau2, z_out, gate, N);

    const int NGB = ((N + 15) / 16) * 8;     // node-groups x 8 col-slices
    k_gather_cs<<<NGB, 256, 0, stream>>>(h, off, cnt, eidx, gate, norm, out, N);
}

// Round 8
// 309.332 us; speedup vs baseline: 1.2170x; 1.2170x over previous
//
#include <hip/hip_runtime.h>
#include <math.h>

#define CN 32    // classes
#define DN 128   // feature dim
#define BKT_SHIFT 9          // 512 nodes per bucket
#define BKT_NODES 512
#define CHUNK 8192           // edges per partition chunk
#define MAXBKT 1024
#define DCAP 12288           // max edges per bucket (mean 8192, huge sigma headroom)

// ---------------- softmax over C per node: 32 threads/node ----------------
__global__ void k_softmax(const float* __restrict__ logits, float* __restrict__ probs, int N) {
    int t = blockIdx.x * blockDim.x + threadIdx.x;
    int node = t >> 5, c = t & 31;
    if (node >= N) return;
    float l = logits[node * CN + c];
    float m = l;
    #pragma unroll
    for (int o = 16; o; o >>= 1) m = fmaxf(m, __shfl_xor(m, o, 32));
    float e = __expf(l - m);
    float s = e;
    #pragma unroll
    for (int o = 16; o; o >>= 1) s += __shfl_xor(s, o, 32);
    probs[node * CN + c] = e / s;
}

// ---- pass A: per-chunk bucket histogram. grid = NCH x 256 ----
__global__ void k_part_hist(const int* __restrict__ dst, int* __restrict__ M,
                            int E, int NBKT) {
    __shared__ int hist[MAXBKT];
    int t = threadIdx.x;
    for (int j = t; j < NBKT; j += 256) hist[j] = 0;
    __syncthreads();
    int ebeg = blockIdx.x * CHUNK;
    #pragma unroll
    for (int k = 0; k < CHUNK / 256; ++k) {
        int e = ebeg + k * 256 + t;
        if (e < E) atomicAdd(&hist[dst[e] >> BKT_SHIFT], 1);
    }
    __syncthreads();
    int* row = M + (size_t)blockIdx.x * NBKT;
    for (int j = t; j < NBKT; j += 256) row[j] = hist[j];
}

// ---- pass B: exclusive scan of M in bucket-major order ----
__global__ void k_part_scan(int* __restrict__ M, int* __restrict__ bbase,
                            int NCH, int NBKT, int E) {
    __shared__ int wsum[16], wpre[16];
    __shared__ int carry;
    int t = threadIdx.x, ln = t & 63, wv = t >> 6;
    if (t == 0) carry = 0;
    __syncthreads();
    int L = NCH * NBKT;
    for (int base = 0; base < L; base += 1024) {
        int k = base + t;
        int idx = 0, v = 0;
        if (k < L) {
            int b = k / NCH, ch = k - b * NCH;
            idx = ch * NBKT + b;
            v = M[idx];
        }
        int incl = v;
        #pragma unroll
        for (int o = 1; o < 64; o <<= 1) { int u = __shfl_up(incl, o, 64); if (ln >= o) incl += u; }
        if (ln == 63) wsum[wv] = incl;
        __syncthreads();
        if (t == 0) {
            int r = carry;
            #pragma unroll
            for (int w = 0; w < 16; ++w) { wpre[w] = r; r += wsum[w]; }
            carry = r;
        }
        __syncthreads();
        if (k < L) M[idx] = wpre[wv] + incl - v;
        __syncthreads();
    }
    for (int b = t; b < NBKT; b += 1024) bbase[b] = M[b];
    if (t == 0) bbase[NBKT] = E;
}

// ---- pass C: partition edges into bucket-major slices, packed (local<<17)|src ----
__global__ void k_part_scatter(const int* __restrict__ src, const int* __restrict__ dst,
                               const int* __restrict__ M, int* __restrict__ part,
                               int E, int NBKT) {
    __shared__ int cur[MAXBKT];
    int t = threadIdx.x;
    const int* row = M + (size_t)blockIdx.x * NBKT;
    for (int j = t; j < NBKT; j += 256) cur[j] = row[j];
    __syncthreads();
    int ebeg = blockIdx.x * CHUNK;
    #pragma unroll
    for (int k = 0; k < CHUNK / 256; ++k) {
        int e = ebeg + k * 256 + t;
        if (e < E) {
            int d = dst[e];
            int b = d >> BKT_SHIFT;
            int p = atomicAdd(&cur[b], 1);
            part[p] = ((d & (BKT_NODES - 1)) << 17) | src[e];
        }
    }
}

// ---- pass D: per-bucket LDS counting sort IN PLACE: part slice -> eidx slice ----
__global__ void k_bucket_csr(int* __restrict__ part, const int* __restrict__ bbase,
                             int* __restrict__ cnt, int* __restrict__ off, int N) {
    __shared__ int sbuf[DCAP];
    __shared__ int hcnt[BKT_NODES];
    __shared__ int wsum[8], wpre[8];
    int t = threadIdx.x, ln = t & 63, wv = t >> 6;
    int b = blockIdx.x;
    int lo = bbase[b], hi = bbase[b + 1];
    int n = hi - lo;
    if (n > DCAP) n = DCAP;                 // statistically unreachable
    for (int e = t; e < n; e += BKT_NODES) sbuf[e] = part[lo + e];
    hcnt[t] = 0;
    __syncthreads();
    for (int e = t; e < n; e += BKT_NODES) atomicAdd(&hcnt[sbuf[e] >> 17], 1);
    __syncthreads();
    int v = hcnt[t];
    int incl = v;
    #pragma unroll
    for (int o = 1; o < 64; o <<= 1) { int u = __shfl_up(incl, o, 64); if (ln >= o) incl += u; }
    if (ln == 63) wsum[wv] = incl;
    __syncthreads();
    if (t == 0) {
        int r = 0;
        #pragma unroll
        for (int w = 0; w < 8; ++w) { wpre[w] = r; r += wsum[w]; }
    }
    __syncthreads();
    int excl = wpre[wv] + incl - v;
    int g = b * BKT_NODES + t;
    if (g < N) { cnt[g] = v; off[g] = lo + excl; }
    hcnt[t] = excl;          // per-node cursor
    __syncthreads();
    for (int e = t; e < n; e += BKT_NODES) {
        int pk = sbuf[e];
        int p = atomicAdd(&hcnt[pk >> 17], 1);
        part[lo + p] = pk & 0x1FFFF;        // in-place: now eidx
    }
}

// ---- FUSED: block-specialized { probs_f | raw h-agg } ----
// blocks [0,NBF): gather probs + KL/entropy + per-block LN partials (32 thr/node)
// blocks [NBF,..): gather h rows, write RAW agg (no gate) into aggout
__global__ void k_fused(const float* __restrict__ probs, const int* __restrict__ off,
                        const int* __restrict__ cnt, const int* __restrict__ eidx,
                        float* __restrict__ f1buf, float* __restrict__ f2buf,
                        double* __restrict__ pbuf,
                        const float* __restrict__ h, float* __restrict__ aggout,
                        int N, int NBF) {
    if ((int)blockIdx.x < NBF) {
        int t = blockIdx.x * blockDim.x + threadIdx.x;
        int i = t >> 5, c = t & 31;
        float f1 = 0.f, f2 = 0.f;
        if (i < N) {
            int beg = off[i], dg = cnt[i];
            float sum = 0.f;
            for (int base = 0; base < dg; base += 16) {
                int rem = dg - base;
                int lim = rem < 16 ? rem : 16;
                int myi = (c < lim) ? eidx[beg + base + c] : 0;
                #pragma unroll
                for (int j = 0; j < 16; ++j) {
                    int s = __shfl(myi, j, 32);
                    float v = probs[(size_t)s * CN + c];
                    sum += (j < rem) ? v : 0.f;
                }
            }
            float f1c = 0.f, f2c = 0.f;
            if (dg > 0) {
                float p = probs[(size_t)i * CN + c];
                float mp = sum / (float)dg;
                float lm = logf(mp + 1e-9f);
                f1c = p * (logf(p + 1e-9f) - lm);
                f2c = -mp * lm;
            }
            #pragma unroll
            for (int o = 16; o; o >>= 1) { f1c += __shfl_xor(f1c, o, 32); f2c += __shfl_xor(f2c, o, 32); }
            if (c == 0) { f1buf[i] = f1c; f2buf[i] = f2c; f1 = f1c; f2 = f2c; }
        }
        double v0 = f1, v1 = (double)f1 * f1, v2 = f2, v3 = (double)f2 * f2;
        #pragma unroll
        for (int o = 32; o; o >>= 1) {
            v0 += __shfl_down(v0, o, 64);
            v1 += __shfl_down(v1, o, 64);
            v2 += __shfl_down(v2, o, 64);
            v3 += __shfl_down(v3, o, 64);
        }
        __shared__ double sh[4][4];
        int wave = threadIdx.x >> 6, lane = threadIdx.x & 63;
        if (lane == 0) { sh[0][wave] = v0; sh[1][wave] = v1; sh[2][wave] = v2; sh[3][wave] = v3; }
        __syncthreads();
        if (threadIdx.x == 0) {
            double a = 0, b = 0, c2 = 0, d = 0;
            #pragma unroll
            for (int w = 0; w < 4; ++w) { a += sh[0][w]; b += sh[1][w]; c2 += sh[2][w]; d += sh[3][w]; }
            double* p = pbuf + (size_t)blockIdx.x * 4;
            p[0] = a; p[1] = b; p[2] = c2; p[3] = d;
        }
    } else {
        int bb = blockIdx.x - NBF;
        int t = bb * blockDim.x + threadIdx.x;
        int i = t >> 6, ln = t & 63;
        if (i >= N) return;
        int beg = off[i], dg = cnt[i];
        const float2* h2 = (const float2*)h;
        float ax = 0.f, ay = 0.f;
        for (int base = 0; base < dg; base += 16) {
            int rem = dg - base;
            int lim = rem < 16 ? rem : 16;
            int myi = (ln < lim) ? eidx[beg + base + ln] : 0;
            #pragma unroll
            for (int j = 0; j < 16; ++j) {
                int s = __shfl(myi, j, 64);
                float2 v = h2[(size_t)s * 64 + ln];
                bool use = j < rem;
                ax += use ? v.x : 0.f;
                ay += use ? v.y : 0.f;
            }
        }
        float2 r; r.x = ax; r.y = ay;
        ((float2*)aggout)[(size_t)i * 64 + ln] = r;   // raw agg
    }
}

// ---- deterministic single-block reduction of block partials -> stats ----
__global__ void k_redstats(const double* __restrict__ pbuf, double* __restrict__ stats, int nblk) {
    int t = threadIdx.x;
    double a = 0, b = 0, c = 0, d = 0;
    for (int k = t; k < nblk; k += blockDim.x) {
        const double* p = pbuf + (size_t)k * 4;
        a += p[0]; b += p[1]; c += p[2]; d += p[3];
    }
    #pragma unroll
    for (int o = 32; o; o >>= 1) {
        a += __shfl_down(a, o, 64);
        b += __shfl_down(b, o, 64);
        c += __shfl_down(c, o, 64);
        d += __shfl_down(d, o, 64);
    }
    __shared__ double sh[4][16];
    int wv = t >> 6, ln = t & 63;
    if (ln == 0) { sh[0][wv] = a; sh[1][wv] = b; sh[2][wv] = c; sh[3][wv] = d; }
    __syncthreads();
    if (t == 0) {
        double s0 = 0, s1 = 0, s2 = 0, s3 = 0;
        int nw = blockDim.x >> 6;
        for (int w = 0; w < nw; ++w) { s0 += sh[0][w]; s1 += sh[1][w]; s2 += sh[2][w]; s3 += sh[3][w]; }
        stats[0] = s0; stats[1] = s1; stats[2] = s2; stats[3] = s3;
    }
}

// ---- z + gate + epilogue, fused: 32 lanes (float4) per node ----
// out currently holds raw agg; rewrite in place: out = h + gate*relu(agg*norm)
__global__ void k_z_ep(const float* __restrict__ f1buf, const float* __restrict__ f2buf,
                       const double* __restrict__ stats, const float* __restrict__ old_z,
                       const float* __restrict__ tau1, const float* __restrict__ tau2,
                       const float* __restrict__ h, const float* __restrict__ norm,
                       float* __restrict__ out, float* __restrict__ z_out, int N) {
    int t = blockIdx.x * blockDim.x + threadIdx.x;
    int i = t >> 5, c = t & 31;
    if (i >= N) return;
    double invN = 1.0 / (double)N;
    float mu1 = (float)(stats[0] * invN);
    float var1 = (float)(stats[1] * invN) - mu1 * mu1;
    float is1 = rsqrtf(var1 + 1e-5f);
    float mu2 = (float)(stats[2] * invN);
    float var2 = (float)(stats[3] * invN) - mu2 * mu2;
    float is2 = rsqrtf(var2 + 1e-5f);
    float a = (f1buf[i] - mu1) * is1;
    float b = (f2buf[i] - mu2) * is2;
    float z = (1.f / (1.f + __expf(a - tau1[0]))) * (1.f / (1.f + __expf(b - tau2[0])));
    if (c == 0) z_out[i] = z;
    float g = fminf(old_z[i], z);
    float nm = norm[i];
    float4 av = ((const float4*)out)[(size_t)i * 32 + c];
    float4 hv = ((const float4*)h)[(size_t)i * 32 + c];
    float4 r;
    r.x = hv.x + g * fmaxf(av.x * nm, 0.f);
    r.y = hv.y + g * fmaxf(av.y * nm, 0.f);
    r.z = hv.z + g * fmaxf(av.z * nm, 0.f);
    r.w = hv.w + g * fmaxf(av.w * nm, 0.f);
    ((float4*)out)[(size_t)i * 32 + c] = r;
}

extern "C" void kernel_launch(void* const* d_in, const int* in_sizes, int n_in,
                              void* d_out, int out_size, void* d_ws, size_t ws_size,
                              hipStream_t stream) {
    const float* h      = (const float*)d_in[0];
    const float* logits = (const float*)d_in[1];
    const float* old_z  = (const float*)d_in[2];
    const float* norm   = (const float*)d_in[3];
    const float* tau1   = (const float*)d_in[4];
    const float* tau2   = (const float*)d_in[5];
    const int*   src    = (const int*)d_in[6];
    const int*   dst    = (const int*)d_in[7];
    const int N = in_sizes[2];   // old_z length
    const int E = in_sizes[6];   // src length

    float* out   = (float*)d_out;            // [N*DN] new_h, then [N] z
    float* z_out = out + (size_t)N * DN;

    const int B = 256;
    const int NBF  = (N * CN + B - 1) / B;            // probs_f blocks
    const int NG   = (N * 64 + B - 1) / B;            // h-agg blocks
    const int NBKT = (N + BKT_NODES - 1) >> BKT_SHIFT;
    const int NCH  = (E + CHUNK - 1) / CHUNK;

    // workspace layout
    char*   ws    = (char*)d_ws;
    double* stats = (double*)ws;                         // 64 B
    int*    cnt   = (int*)(ws + 64);                     // N
    int*    off   = cnt + N;                             // N
    int*    bbase = off + N;                             // MAXBKT+8
    int*    M     = bbase + MAXBKT + 8;                  // NCH*NBKT
    int*    eidx  = M + (size_t)NCH * NBKT;              // E (part, sorted in place)
    float*  probs = (float*)(eidx + E);                  // N*CN
    float*  f1buf = probs + (size_t)N * CN;              // N
    float*  f2buf = f1buf + N;                           // N
    double* pbuf  = (double*)(((size_t)(f2buf + N) + 15) & ~(size_t)15);  // NBF*4

    k_softmax<<<(N * CN + B - 1) / B, B, 0, stream>>>(logits, probs, N);

    k_part_hist<<<NCH, 256, 0, stream>>>(dst, M, E, NBKT);
    k_part_scan<<<1, 1024, 0, stream>>>(M, bbase, NCH, NBKT, E);
    k_part_scatter<<<NCH, 256, 0, stream>>>(src, dst, M, eidx, E, NBKT);
    k_bucket_csr<<<NBKT, BKT_NODES, 0, stream>>>(eidx, bbase, cnt, off, N);

    k_fused<<<NBF + NG, B, 0, stream>>>(probs, off, cnt, eidx, f1buf, f2buf, pbuf,
                                        h, out, N, NBF);
    k_redstats<<<1, 1024, 0, stream>>>(pbuf, stats, NBF);
    k_z_ep<<<(N * 32 + B - 1) / B, B, 0, stream>>>(f1buf, f2buf, stats, old_z, tau1, tau2,
                                                   h, norm, out, z_out, N);
}

// Round 10
// 248.976 us; speedup vs baseline: 1.5120x; 1.2424x over previous
//
#include <hip/hip_runtime.h>
#include <math.h>

#define CN 32    // classes
#define DN 128   // feature dim
#define BKT_SHIFT 9          // 512 nodes per bucket
#define BKT_NODES 512
#define CHUNK 8192           // edges per partition chunk
#define MAXBKT 1024
#define DCAP 12288           // max edges per bucket (mean 8192, huge sigma headroom)
#define NSLICE 4             // h-gather column slices (32 cols = 128 B each)

// ---- FUSED: block-specialized { dst-histogram | softmax } ----
// blocks [0,NCH): per-chunk bucket histogram; blocks [NCH,..): softmax (32 thr/node)
__global__ void k_sm_hist(const int* __restrict__ dst, int* __restrict__ M,
                          const float* __restrict__ logits, float* __restrict__ probs,
                          int E, int NBKT, int NCH, int N) {
    if ((int)blockIdx.x < NCH) {
        __shared__ int hist[MAXBKT];
        int t = threadIdx.x;
        for (int j = t; j < NBKT; j += 256) hist[j] = 0;
        __syncthreads();
        int ebeg = blockIdx.x * CHUNK;
        #pragma unroll
        for (int k = 0; k < CHUNK / 256; ++k) {
            int e = ebeg + k * 256 + t;
            if (e < E) atomicAdd(&hist[dst[e] >> BKT_SHIFT], 1);
        }
        __syncthreads();
        int* row = M + (size_t)blockIdx.x * NBKT;
        for (int j = t; j < NBKT; j += 256) row[j] = hist[j];
    } else {
        int t = (blockIdx.x - NCH) * blockDim.x + threadIdx.x;
        int node = t >> 5, c = t & 31;
        if (node >= N) return;
        float l = logits[node * CN + c];
        float m = l;
        #pragma unroll
        for (int o = 16; o; o >>= 1) m = fmaxf(m, __shfl_xor(m, o, 32));
        float e = __expf(l - m);
        float s = e;
        #pragma unroll
        for (int o = 16; o; o >>= 1) s += __shfl_xor(s, o, 32);
        probs[node * CN + c] = e / s;
    }
}

// ---- scan A: per-bucket exclusive scan over chunks (grid = NBKT, 256 thr) ----
// M[ch][b] -> exclusive prefix over ch within bucket b; bsum[b] = total
__global__ void k_scan_a(int* __restrict__ M, int* __restrict__ bsum, int NCH, int NBKT) {
    int b = blockIdx.x;
    int t = threadIdx.x, ln = t & 63, wv = t >> 6;
    int v = (t < NCH) ? M[(size_t)t * NBKT + b] : 0;
    int incl = v;
    #pragma unroll
    for (int o = 1; o < 64; o <<= 1) { int u = __shfl_up(incl, o, 64); if (ln >= o) incl += u; }
    __shared__ int wsum[4], wpre[4];
    if (ln == 63) wsum[wv] = incl;
    __syncthreads();
    if (t == 0) {
        int r = 0;
        for (int w = 0; w < 4; ++w) { wpre[w] = r; r += wsum[w]; }
    }
    __syncthreads();
    int excl = wpre[wv] + incl - v;
    if (t < NCH) M[(size_t)t * NBKT + b] = excl;
    if (t == 255) bsum[b] = excl + v;   // t=255 >= NCH, so excl == bucket total
}

// ---- scan B: exclusive scan of bucket totals -> bbase (1 block, 256 thr) ----
__global__ void k_scan_b(const int* __restrict__ bsum, int* __restrict__ bbase, int NBKT, int E) {
    int t = threadIdx.x, ln = t & 63, wv = t >> 6;
    int v = (t < NBKT) ? bsum[t] : 0;
    int incl = v;
    #pragma unroll
    for (int o = 1; o < 64; o <<= 1) { int u = __shfl_up(incl, o, 64); if (ln >= o) incl += u; }
    __shared__ int wsum[4], wpre[4];
    if (ln == 63) wsum[wv] = incl;
    __syncthreads();
    if (t == 0) {
        int r = 0;
        for (int w = 0; w < 4; ++w) { wpre[w] = r; r += wsum[w]; }
    }
    __syncthreads();
    if (t < NBKT) bbase[t] = wpre[wv] + incl - v;
    if (t == 0) bbase[NBKT] = E;
}

// ---- pass C: partition edges into bucket-major slices, packed (local<<17)|src ----
__global__ void k_part_scatter(const int* __restrict__ src, const int* __restrict__ dst,
                               const int* __restrict__ M, const int* __restrict__ bbase,
                               int* __restrict__ part, int E, int NBKT) {
    __shared__ int cur[MAXBKT];
    int t = threadIdx.x;
    const int* row = M + (size_t)blockIdx.x * NBKT;
    for (int j = t; j < NBKT; j += 256) cur[j] = row[j] + bbase[j];
    __syncthreads();
    int ebeg = blockIdx.x * CHUNK;
    #pragma unroll
    for (int k = 0; k < CHUNK / 256; ++k) {
        int e = ebeg + k * 256 + t;
        if (e < E) {
            int d = dst[e];
            int b = d >> BKT_SHIFT;
            int p = atomicAdd(&cur[b], 1);
            part[p] = ((d & (BKT_NODES - 1)) << 17) | src[e];
        }
    }
}

// ---- pass D: per-bucket LDS counting sort IN PLACE: part slice -> eidx slice ----
__global__ void k_bucket_csr(int* __restrict__ part, const int* __restrict__ bbase,
                             int* __restrict__ cnt, int* __restrict__ off, int N) {
    __shared__ int sbuf[DCAP];
    __shared__ int hcnt[BKT_NODES];
    __shared__ int wsum[8], wpre[8];
    int t = threadIdx.x, ln = t & 63, wv = t >> 6;
    int b = blockIdx.x;
    int lo = bbase[b], hi = bbase[b + 1];
    int n = hi - lo;
    if (n > DCAP) n = DCAP;                 // statistically unreachable
    for (int e = t; e < n; e += BKT_NODES) sbuf[e] = part[lo + e];
    hcnt[t] = 0;
    __syncthreads();
    for (int e = t; e < n; e += BKT_NODES) atomicAdd(&hcnt[sbuf[e] >> 17], 1);
    __syncthreads();
    int v = hcnt[t];
    int incl = v;
    #pragma unroll
    for (int o = 1; o < 64; o <<= 1) { int u = __shfl_up(incl, o, 64); if (ln >= o) incl += u; }
    if (ln == 63) wsum[wv] = incl;
    __syncthreads();
    if (t == 0) {
        int r = 0;
        #pragma unroll
        for (int w = 0; w < 8; ++w) { wpre[w] = r; r += wsum[w]; }
    }
    __syncthreads();
    int excl = wpre[wv] + incl - v;
    int g = b * BKT_NODES + t;
    if (g < N) { cnt[g] = v; off[g] = lo + excl; }
    hcnt[t] = excl;          // per-node cursor
    __syncthreads();
    for (int e = t; e < n; e += BKT_NODES) {
        int pk = sbuf[e];
        int p = atomicAdd(&hcnt[pk >> 17], 1);
        part[lo + p] = pk & 0x1FFFF;        // in-place: now eidx
    }
}

// ---- FUSED: block-specialized { slice-sequential raw h-agg | probs_f } ----
// blocks [0, NSLICE*NGS): h-gather, slice = blk/NGS (32 cols, one 128B granule),
//   dispatched slice-major so per-phase h working set is N*128B = 12.8 MB.
// blocks [NSLICE*NGS, +NBF): gather probs + KL/entropy + per-block LN partials.
__global__ void k_fused(const float* __restrict__ probs, const int* __restrict__ off,
                        const int* __restrict__ cnt, const int* __restrict__ eidx,
                        float* __restrict__ f1buf, float* __restrict__ f2buf,
                        double* __restrict__ pbuf,
                        const float* __restrict__ h, float* __restrict__ aggout,
                        int N, int NGS, int NBF) {
    const int HB = NSLICE * NGS;
    if ((int)blockIdx.x < HB) {
        int slice = blockIdx.x / NGS;
        int g = (blockIdx.x - slice * NGS) * 16 + (threadIdx.x >> 4);
        int c = threadIdx.x & 15;
        if (g >= N) return;
        int beg = off[g], dg = cnt[g];
        const float2* h2 = (const float2*)h;            // row stride 64 float2
        size_t coloff = (size_t)slice * 16 + c;         // float2 index in row
        float ax = 0.f, ay = 0.f;
        for (int base = 0; base < dg; base += 16) {
            int rem = dg - base;
            int lim = rem < 16 ? rem : 16;
            int myi = (c < lim) ? __builtin_nontemporal_load(&eidx[beg + base + c]) : 0;
            #pragma unroll
            for (int j = 0; j < 16; ++j) {
                int s = __shfl(myi, j, 16);
                float2 v = h2[(size_t)s * 64 + coloff]; // 16 lanes = one 128B line
                bool use = j < rem;
                ax += use ? v.x : 0.f;
                ay += use ? v.y : 0.f;
            }
        }
        float* op = (float*)&((float2*)aggout)[(size_t)g * 64 + coloff];
        __builtin_nontemporal_store(ax, op);
        __builtin_nontemporal_store(ay, op + 1);
    } else {
        int pb = blockIdx.x - HB;
        int t = pb * blockDim.x + threadIdx.x;
        int i = t >> 5, c = t & 31;
        float f1 = 0.f, f2 = 0.f;
        if (i < N) {
            int beg = off[i], dg = cnt[i];
            float sum = 0.f;
            for (int base = 0; base < dg; base += 16) {
                int rem = dg - base;
                int lim = rem < 16 ? rem : 16;
                int myi = (c < lim) ? __builtin_nontemporal_load(&eidx[beg + base + c]) : 0;
                #pragma unroll
                for (int j = 0; j < 16; ++j) {
                    int s = __shfl(myi, j, 32);
                    float v = probs[(size_t)s * CN + c];
                    sum += (j < rem) ? v : 0.f;
                }
            }
            float f1c = 0.f, f2c = 0.f;
            if (dg > 0) {
                float p = probs[(size_t)i * CN + c];
                float mp = sum / (float)dg;
                float lm = logf(mp + 1e-9f);
                f1c = p * (logf(p + 1e-9f) - lm);
                f2c = -mp * lm;
            }
            #pragma unroll
            for (int o = 16; o; o >>= 1) { f1c += __shfl_xor(f1c, o, 32); f2c += __shfl_xor(f2c, o, 32); }
            if (c == 0) { f1buf[i] = f1c; f2buf[i] = f2c; f1 = f1c; f2 = f2c; }
        }
        double v0 = f1, v1 = (double)f1 * f1, v2 = f2, v3 = (double)f2 * f2;
        #pragma unroll
        for (int o = 32; o; o >>= 1) {
            v0 += __shfl_down(v0, o, 64);
            v1 += __shfl_down(v1, o, 64);
            v2 += __shfl_down(v2, o, 64);
            v3 += __shfl_down(v3, o, 64);
        }
        __shared__ double sh[4][4];
        int wave = threadIdx.x >> 6, lane = threadIdx.x & 63;
        if (lane == 0) { sh[0][wave] = v0; sh[1][wave] = v1; sh[2][wave] = v2; sh[3][wave] = v3; }
        __syncthreads();
        if (threadIdx.x == 0) {
            double a = 0, b = 0, c2 = 0, d = 0;
            #pragma unroll
            for (int w = 0; w < 4; ++w) { a += sh[0][w]; b += sh[1][w]; c2 += sh[2][w]; d += sh[3][w]; }
            double* p = pbuf + (size_t)pb * 4;
            p[0] = a; p[1] = b; p[2] = c2; p[3] = d;
        }
    }
}

// ---- deterministic single-block reduction of block partials -> stats ----
__global__ void k_redstats(const double* __restrict__ pbuf, double* __restrict__ stats, int nblk) {
    int t = threadIdx.x;
    double a = 0, b = 0, c = 0, d = 0;
    for (int k = t; k < nblk; k += blockDim.x) {
        const double* p = pbuf + (size_t)k * 4;
        a += p[0]; b += p[1]; c += p[2]; d += p[3];
    }
    #pragma unroll
    for (int o = 32; o; o >>= 1) {
        a += __shfl_down(a, o, 64);
        b += __shfl_down(b, o, 64);
        c += __shfl_down(c, o, 64);
        d += __shfl_down(d, o, 64);
    }
    __shared__ double sh[4][16];
    int wv = t >> 6, ln = t & 63;
    if (ln == 0) { sh[0][wv] = a; sh[1][wv] = b; sh[2][wv] = c; sh[3][wv] = d; }
    __syncthreads();
    if (t == 0) {
        double s0 = 0, s1 = 0, s2 = 0, s3 = 0;
        int nw = blockDim.x >> 6;
        for (int w = 0; w < nw; ++w) { s0 += sh[0][w]; s1 += sh[1][w]; s2 += sh[2][w]; s3 += sh[3][w]; }
        stats[0] = s0; stats[1] = s1; stats[2] = s2; stats[3] = s3;
    }
}

// ---- z + gate + epilogue, fused: 32 lanes (float4) per node ----
// out currently holds raw agg; rewrite in place: out = h + gate*relu(agg*norm)
__global__ void k_z_ep(const float* __restrict__ f1buf, const float* __restrict__ f2buf,
                       const double* __restrict__ stats, const float* __restrict__ old_z,
                       const float* __restrict__ tau1, const float* __restrict__ tau2,
                       const float* __restrict__ h, const float* __restrict__ norm,
                       float* __restrict__ out, float* __restrict__ z_out, int N) {
    int t = blockIdx.x * blockDim.x + threadIdx.x;
    int i = t >> 5, c = t & 31;
    if (i >= N) return;
    double invN = 1.0 / (double)N;
    float mu1 = (float)(stats[0] * invN);
    float var1 = (float)(stats[1] * invN) - mu1 * mu1;
    float is1 = rsqrtf(var1 + 1e-5f);
    float mu2 = (float)(stats[2] * invN);
    float var2 = (float)(stats[3] * invN) - mu2 * mu2;
    float is2 = rsqrtf(var2 + 1e-5f);
    float a = (f1buf[i] - mu1) * is1;
    float b = (f2buf[i] - mu2) * is2;
    float z = (1.f / (1.f + __expf(a - tau1[0]))) * (1.f / (1.f + __expf(b - tau2[0])));
    if (c == 0) z_out[i] = z;
    float g = fminf(old_z[i], z);
    float nm = norm[i];
    float4 av = ((const float4*)out)[(size_t)i * 32 + c];
    float4 hv = ((const float4*)h)[(size_t)i * 32 + c];
    float4 r;
    r.x = hv.x + g * fmaxf(av.x * nm, 0.f);
    r.y = hv.y + g * fmaxf(av.y * nm, 0.f);
    r.z = hv.z + g * fmaxf(av.z * nm, 0.f);
    r.w = hv.w + g * fmaxf(av.w * nm, 0.f);
    ((float4*)out)[(size_t)i * 32 + c] = r;
}

extern "C" void kernel_launch(void* const* d_in, const int* in_sizes, int n_in,
                              void* d_out, int out_size, void* d_ws, size_t ws_size,
                              hipStream_t stream) {
    const float* h      = (const float*)d_in[0];
    const float* logits = (const float*)d_in[1];
    const float* old_z  = (const float*)d_in[2];
    const float* norm   = (const float*)d_in[3];
    const float* tau1   = (const float*)d_in[4];
    const float* tau2   = (const float*)d_in[5];
    const int*   src    = (const int*)d_in[6];
    const int*   dst    = (const int*)d_in[7];
    const int N = in_sizes[2];   // old_z length
    const int E = in_sizes[6];   // src length

    float* out   = (float*)d_out;            // [N*DN] new_h, then [N] z
    float* z_out = out + (size_t)N * DN;

    const int B = 256;
    const int NBF  = (N * CN + B - 1) / B;            // probs_f blocks
    const int NGS  = (N + 15) / 16;                   // h-agg blocks per slice
    const int NBKT = (N + BKT_NODES - 1) >> BKT_SHIFT;
    const int NCH  = (E + CHUNK - 1) / CHUNK;         // must be <= 256 for k_scan_a

    // workspace layout
    char*   ws    = (char*)d_ws;
    double* stats = (double*)ws;                         // 64 B
    int*    cnt   = (int*)(ws + 64);                     // N
    int*    off   = cnt + N;                             // N
    int*    bbase = off + N;                             // MAXBKT+8
    int*    bsum  = bbase + MAXBKT + 8;                  // MAXBKT
    int*    M     = bsum + MAXBKT;                       // NCH*NBKT
    int*    eidx  = M + (size_t)NCH * NBKT;              // E (part, sorted in place)
    float*  probs = (float*)(eidx + E);                  // N*CN
    float*  f1buf = probs + (size_t)N * CN;              // N
    float*  f2buf = f1buf + N;                           // N
    double* pbuf  = (double*)(((size_t)(f2buf + N) + 15) & ~(size_t)15);  // NBF*4

    k_sm_hist<<<NCH + NBF, B, 0, stream>>>(dst, M, logits, probs, E, NBKT, NCH, N);
    k_scan_a<<<NBKT, 256, 0, stream>>>(M, bsum, NCH, NBKT);
    k_scan_b<<<1, 256, 0, stream>>>(bsum, bbase, NBKT, E);
    k_part_scatter<<<NCH, 256, 0, stream>>>(src, dst, M, bbase, eidx, E, NBKT);
    k_bucket_csr<<<NBKT, BKT_NODES, 0, stream>>>(eidx, bbase, cnt, off, N);

    k_fused<<<NSLICE * NGS + NBF, B, 0, stream>>>(probs, off, cnt, eidx, f1buf, f2buf, pbuf,
                                                  h, out, N, NGS, NBF);
    k_redstats<<<1, 1024, 0, stream>>>(pbuf, stats, NBF);
    k_z_ep<<<(N * 32 + B - 1) / B, B, 0, stream>>>(f1buf, f2buf, stats, old_z, tau1, tau2,
                                                   h, norm, out, z_out, N);
}